// Round 1
// 460.213 us; speedup vs baseline: 1.0981x; 1.0981x over previous
//
#include <hip/hip_runtime.h>

typedef float f32x4 __attribute__((ext_vector_type(4)));
typedef __bf16 bf16x8 __attribute__((ext_vector_type(8)));
typedef unsigned int u32x4 __attribute__((ext_vector_type(4)));
typedef unsigned short ushort_t;

// ---------------------------------------------------------------- fp32 -> bf16 (RNE)
__device__ __forceinline__ unsigned short f2bf(float f) {
    unsigned u = __float_as_uint(f);
    u += 0x7FFFu + ((u >> 16) & 1u);   // round-nearest-even (inputs finite)
    return (unsigned short)(u >> 16);
}

// One fused cast kernel for both x and W (unchanged from verified R-prev).
__global__ __launch_bounds__(256) void cast_both(const f32x4* __restrict__ x, u32x4* __restrict__ xo,
                                                 const f32x4* __restrict__ w, u32x4* __restrict__ wo) {
    long t = (long)blockIdx.x * 256 + threadIdx.x;
    const f32x4* src;
    u32x4* dst;
    long j;
    if (t < 4194304L) { src = x; dst = xo; j = t; }
    else              { src = w; dst = wo; j = t - 4194304L; }
    f32x4 a = __builtin_nontemporal_load(&src[2 * j]);
    f32x4 b = __builtin_nontemporal_load(&src[2 * j + 1]);
    u32x4 v;
    v.x = (unsigned)f2bf(a.x) | ((unsigned)f2bf(a.y) << 16);
    v.y = (unsigned)f2bf(a.z) | ((unsigned)f2bf(a.w) << 16);
    v.z = (unsigned)f2bf(b.x) | ((unsigned)f2bf(b.y) << 16);
    v.w = (unsigned)f2bf(b.z) | ((unsigned)f2bf(b.w) << 16);
    dst[j] = v;
}

// ---------------------------------------------------------------- 256x256 8-phase bf16 MFMA GEMM
// out[m,n] = sum_k A[m,k]*B[n,k] + bias[n].  A:[8192,4096] bf16, B:[4096,4096] bf16, both row-major.
// BM=BN=256, BK=64, 8 waves (2Mx4N), per-wave output 128x64 as acc[mh][nh][mi][nj] (16x16x32 MFMA).
// LDS 128KiB: A/B x dbuf x half(128rows x 64K).  16B-block XOR swizzle slot = kb ^ (row&7)
// (same involution as verified previous kernel: 0 bank conflicts).
// Schedule (T3+T4+T5, m194-m201 template): 4 phases/tile, quadrants (0,0),(0,1),(1,1),(1,0);
// stages: p0 -> B0(t+1), p1 -> A0(t+2), p2 -> B1(t+2), p3 -> A1(t+2); vmcnt(6) once per tile at p3.
// Each half-region's last ds_read completes (lgkmcnt0 + barrier) one phase before it is restaged.
constexpr int KD = 4096;

#define GLOAD_LDS(gp, lp) __builtin_amdgcn_global_load_lds( \
    (const __attribute__((address_space(1))) unsigned int*)(gp), \
    (__attribute__((address_space(3))) unsigned int*)(lp), 16, 0, 0)

#define BARRIER()    __builtin_amdgcn_s_barrier()
#define WAIT_LGKM0() asm volatile("s_waitcnt lgkmcnt(0)" ::: "memory")
#define WAIT_VM(n)   asm volatile("s_waitcnt vmcnt(" #n ")" ::: "memory")

__global__ __launch_bounds__(512, 2) void gemm256(const ushort_t* __restrict__ A,
                                                  const ushort_t* __restrict__ B,
                                                  const float* __restrict__ bias,
                                                  float* __restrict__ out) {
    __shared__ char lds[131072];
    // A half-tiles at (buf*2+half)*16384, B half-tiles at 65536 + (buf*2+half)*16384

    const int tid  = threadIdx.x;
    const int lane = tid & 63;
    const int wave = tid >> 6;      // 0..7
    const int wr   = wave >> 2;     // 0..1  (M within wave grid)
    const int wc   = wave & 3;      // 0..3  (N within wave grid)
    const int q    = lane >> 4;
    const int ml   = lane & 15;

    // XCD-aware bijective swizzle: 512 blocks, 8 XCDs, 64 per XCD (tm-major within XCD
    // -> 2MB A-panel stays L2-resident per XCD).
    const int bid = blockIdx.x;
    const int swz = (bid & 7) * 64 + (bid >> 3);
    const int m0  = (swz >> 4) * 256;   // 0..31 -> M tiles
    const int n0  = (swz & 15) * 256;   // 0..15 -> N tiles

    // staging geometry: slot s = i*512+tid; row = s>>3; stored col c = s&7; source kb = c ^ (row&7)
    const int srow = tid >> 3;                                  // 0..63
    const int koff = ((tid & 7) ^ (srow & 7)) * 8;              // element offset along K
    const int ldst = tid * 16;                                  // byte offset, inst 0
    const ushort_t* gA = A + (size_t)m0 * KD + koff;
    const ushort_t* gB = B + (size_t)n0 * KD + koff;

#define STAGE_A(buf, half, kt) do { \
    const ushort_t* _g = gA + (size_t)((half) * 128 + srow) * KD + (kt); \
    char* _l = lds + ((buf) * 2 + (half)) * 16384 + ldst; \
    GLOAD_LDS(_g, _l); \
    GLOAD_LDS(_g + (size_t)64 * KD, _l + 8192); \
} while (0)

#define STAGE_B(buf, half, kt) do { \
    const ushort_t* _g = gB + (size_t)((half) * 128 + srow) * KD + (kt); \
    char* _l = lds + 65536 + ((buf) * 2 + (half)) * 16384 + ldst; \
    GLOAD_LDS(_g, _l); \
    GLOAD_LDS(_g + (size_t)64 * KD, _l + 8192); \
} while (0)

    // fragment read byte-offsets within a 16KB half-tile (row&7 == ml&7 for all our rows)
    int offA[4][2], offB[2][2];
#pragma unroll
    for (int mi = 0; mi < 4; ++mi)
#pragma unroll
        for (int s = 0; s < 2; ++s)
            offA[mi][s] = (wr * 64 + mi * 16 + ml) * 128 + (((s * 4 + q) ^ (ml & 7)) << 4);
#pragma unroll
    for (int nj = 0; nj < 2; ++nj)
#pragma unroll
        for (int s = 0; s < 2; ++s)
            offB[nj][s] = (wc * 32 + nj * 16 + ml) * 128 + (((s * 4 + q) ^ (ml & 7)) << 4);

    f32x4 acc[2][2][4][2];
#pragma unroll
    for (int a = 0; a < 2; ++a)
#pragma unroll
        for (int c = 0; c < 2; ++c)
#pragma unroll
            for (int d = 0; d < 4; ++d)
#pragma unroll
                for (int e = 0; e < 2; ++e) {
                    acc[a][c][d][e].x = 0.f; acc[a][c][d][e].y = 0.f;
                    acc[a][c][d][e].z = 0.f; acc[a][c][d][e].w = 0.f;
                }
    bf16x8 av[4][2], bv[2][2];

#define LOAD_AV(buf, mh) do { \
    const char* _b = lds + ((buf) * 2 + (mh)) * 16384; \
    _Pragma("unroll") for (int mi = 0; mi < 4; ++mi) \
    _Pragma("unroll") for (int s = 0; s < 2; ++s) \
        av[mi][s] = *(const bf16x8*)(_b + offA[mi][s]); \
} while (0)

#define LOAD_BV(buf, nh) do { \
    const char* _b = lds + 65536 + ((buf) * 2 + (nh)) * 16384; \
    _Pragma("unroll") for (int nj = 0; nj < 2; ++nj) \
    _Pragma("unroll") for (int s = 0; s < 2; ++s) \
        bv[nj][s] = *(const bf16x8*)(_b + offB[nj][s]); \
} while (0)

#define MFMA_Q(mh, nh) do { \
    __builtin_amdgcn_s_setprio(1); \
    _Pragma("unroll") for (int s = 0; s < 2; ++s) \
    _Pragma("unroll") for (int mi = 0; mi < 4; ++mi) \
    _Pragma("unroll") for (int nj = 0; nj < 2; ++nj) \
        acc[mh][nh][mi][nj] = __builtin_amdgcn_mfma_f32_16x16x32_bf16(av[mi][s], bv[nj][s], acc[mh][nh][mi][nj], 0, 0, 0); \
    __builtin_amdgcn_s_setprio(0); \
} while (0)

#define TILE_BODY(b, STG0, STG1, STG2, STG3, VMW) do { \
    LOAD_AV(b, 0); LOAD_BV(b, 0); STG0; \
    BARRIER(); WAIT_LGKM0(); MFMA_Q(0, 0); BARRIER(); \
    LOAD_BV(b, 1); STG1; \
    BARRIER(); WAIT_LGKM0(); MFMA_Q(0, 1); BARRIER(); \
    LOAD_AV(b, 1); STG2; \
    BARRIER(); WAIT_LGKM0(); MFMA_Q(1, 1); BARRIER(); \
    LOAD_BV(b, 0); STG3; VMW; \
    BARRIER(); WAIT_LGKM0(); MFMA_Q(1, 0); BARRIER(); \
} while (0)

    // prologue: tile0 fully (A0,B0,B1,A1) + tile1 (A0,B1,A1); B0(1) comes at p0(0).
    // vmcnt(6): tile0's 8 loads landed, tile1's 3 half-tiles in flight.
    STAGE_A(0, 0, 0);  STAGE_B(0, 0, 0);  STAGE_B(0, 1, 0);  STAGE_A(0, 1, 0);
    STAGE_A(1, 0, 64); STAGE_B(1, 1, 64); STAGE_A(1, 1, 64);
    WAIT_VM(6);
    BARRIER();

    // main loop: tiles 0..61 (pairs), steady staging; vmcnt(6) at each p3 lands tile t+1 entirely.
    for (int tp = 0; tp < 31; ++tp) {
        const int kt = tp * 128;
        TILE_BODY(0, STAGE_B(1, 0, kt + 64),  STAGE_A(0, 0, kt + 128),
                     STAGE_B(0, 1, kt + 128), STAGE_A(0, 1, kt + 128), WAIT_VM(6));
        TILE_BODY(1, STAGE_B(0, 0, kt + 128), STAGE_A(1, 0, kt + 192),
                     STAGE_B(1, 1, kt + 192), STAGE_A(1, 1, kt + 192), WAIT_VM(6));
    }
    // epilogue tiles: 62 stages only B0(63) and drains; 63 pure compute.
    TILE_BODY(0, STAGE_B(1, 0, 4032), (void)0, (void)0, (void)0, WAIT_VM(0));
    TILE_BODY(1, (void)0, (void)0, (void)0, (void)0, (void)0);

    // epilogue: C/D layout col=lane&15, row=q*4+reg
    float bb[2][2];
#pragma unroll
    for (int nh = 0; nh < 2; ++nh)
#pragma unroll
        for (int nj = 0; nj < 2; ++nj)
            bb[nh][nj] = bias[n0 + nh * 128 + wc * 32 + nj * 16 + ml];

#pragma unroll
    for (int mh = 0; mh < 2; ++mh)
#pragma unroll
        for (int nh = 0; nh < 2; ++nh)
#pragma unroll
            for (int mi = 0; mi < 4; ++mi)
#pragma unroll
                for (int nj = 0; nj < 2; ++nj) {
                    const int gc  = n0 + nh * 128 + wc * 32 + nj * 16 + ml;
                    const int gr0 = m0 + mh * 128 + wr * 64 + mi * 16 + q * 4;
#pragma unroll
                    for (int r = 0; r < 4; ++r)
                        out[(size_t)(gr0 + r) * 4096 + gc] = acc[mh][nh][mi][nj][r] + bb[nh][nj];
                }
}

// ---------------------------------------------------------------- fp32 fallback (only if ws too small)
__global__ __launch_bounds__(256) void gemm_f32_fallback(const float* __restrict__ x,
                                                         const float* __restrict__ W,
                                                         const float* __restrict__ bias,
                                                         float* __restrict__ out) {
    __shared__ float As[32][33];
    __shared__ float Bs[32][33];
    const int tx = threadIdx.x & 31, ty = threadIdx.x >> 5;   // ty 0..7
    const int m0 = blockIdx.y * 32, n0 = blockIdx.x * 32;
    float acc[4] = {0.f, 0.f, 0.f, 0.f};
    for (int k0 = 0; k0 < 4096; k0 += 32) {
#pragma unroll
        for (int i = 0; i < 4; ++i) {
            As[ty + 8 * i][tx] = x[(size_t)(m0 + ty + 8 * i) * 4096 + k0 + tx];
            Bs[ty + 8 * i][tx] = W[(size_t)(n0 + ty + 8 * i) * 4096 + k0 + tx];
        }
        __syncthreads();
#pragma unroll 8
        for (int kk = 0; kk < 32; ++kk) {
            const float bv = Bs[tx][kk];
#pragma unroll
            for (int i = 0; i < 4; ++i) acc[i] += As[ty + 8 * i][kk] * bv;
        }
        __syncthreads();
    }
#pragma unroll
    for (int i = 0; i < 4; ++i)
        out[(size_t)(m0 + ty + 8 * i) * 4096 + n0 + tx] = acc[i] + bias[n0 + tx];
}

// ---------------------------------------------------------------- launch
extern "C" void kernel_launch(void* const* d_in, const int* in_sizes, int n_in,
                              void* d_out, int out_size, void* d_ws, size_t ws_size,
                              hipStream_t stream) {
    const float* x = (const float*)d_in[0];   // [8192, 4096]
    const float* W = (const float*)d_in[1];   // [4096, 4096]
    const float* b = (const float*)d_in[2];   // [4096]
    float* out = (float*)d_out;               // [8192, 4096]

    constexpr size_t T = 8192, DIN = 4096, DOUT = 4096;
    const size_t nx = T * DIN, nw = DOUT * DIN;

    if (ws_size >= (nx + nw) * sizeof(unsigned short)) {
        unsigned short* xbf = (unsigned short*)d_ws;
        unsigned short* wbf = xbf + nx;
        cast_both<<<24576, 256, 0, stream>>>((const f32x4*)x, (u32x4*)xbf,
                                             (const f32x4*)W, (u32x4*)wbf);
        // 256x256 tiles: (8192/256) x (4096/256) = 32 x 16 = 512 blocks, 512 threads
        gemm256<<<512, 512, 0, stream>>>(xbf, wbf, b, out);
    } else {
        dim3 grid(DOUT / 32, T / 32);
        gemm_f32_fallback<<<grid, 256, 0, stream>>>(x, W, b, out);
    }
}